// Round 8
// baseline (158.251 us; speedup 1.0000x reference)
//
#include <hip/hip_runtime.h>
#include <cstdint>
#include <math.h>

// SoftmaxGaussian: out_mean/out_var over 10000 MC softmax samples with
// JAX threefry2x32-exact random draw (key(42), shape (512,16,10000)).
//
//   N = 512*16*10000 ; half = 40,960,000 = 256*16*10000
//   flat j=(b*16+k)*10000+s ; threefry block i: counters (i, i+half),
//   key (0,42) -> (z[j=i], z[j=i+half]) => one call yields (b,k,s) AND
//   (b+256,k,s).
//
// R8: R6 (few instrs, 73% busy) and R7 (more instrs, 88% busy) hit the same
// 171 us wall. Keep R7's thin 4-lane cooperative structure (36 VGPR) and:
//   - THREADS=512, SPLIT=4: 4 WGs/CU x 8 waves fills the 2048-thread budget
//   - s-unroll x2: two samples in flight (uses the 28 spare VGPRs as ILP)
//   - wave-uniform tail-skip in erfinv (65% of calls skip 9 FMA + 2 sqrt)
//   - packed f32x2 row-sum shuffles; explicit rotateleft (v_alignbit)
// Per-z numerics bit-identical to R7. Spill tripwire: FETCH_SIZE must stay
// ~0.5 MB; if it balloons the unroll is the suspect.

typedef float f32x2 __attribute__((ext_vector_type(2)));

#define NSAMP 10000
#define HALF_N 40960000u
#define THREADS 512
#define WAVES 8
#define SGROUPS (THREADS / 4)   // 128 s-groups per block

#define LOG2E 1.44269504088896340736f
#define NLN2 -0.69314718055994530942f
#define SQRT_LN2 0.83255461115769775635f
#define TAIL_TH -7.2134752f     // -5/ln2

__device__ __forceinline__ uint32_t rotl32(uint32_t x, int r) {
    return __builtin_rotateleft32(x, (unsigned)r);  // v_alignbit_b32
}

// JAX threefry2x32, key = (0, 42)
__device__ __forceinline__ void tf2x32(uint32_t x0, uint32_t x1,
                                       uint32_t& o0, uint32_t& o1) {
    const uint32_t ks1 = 42u;
    const uint32_t ks2 = 0x1BD11BDAu ^ 42u;
    x1 += ks1;
#define TF_R(r) { x0 += x1; x1 = rotl32(x1, r); x1 ^= x0; }
    TF_R(13) TF_R(15) TF_R(26) TF_R(6)   x0 += ks1; x1 += ks2 + 1u;
    TF_R(17) TF_R(29) TF_R(16) TF_R(24)  x0 += ks2; x1 += 2u;
    TF_R(13) TF_R(15) TF_R(26) TF_R(6)                x1 += ks1 + 3u;
    TF_R(17) TF_R(29) TF_R(16) TF_R(24)  x0 += ks1; x1 += ks2 + 4u;
    TF_R(13) TF_R(15) TF_R(26) TF_R(6)   x0 += ks2; x1 += 5u;
#undef TF_R
    o0 = x0;
    o1 = x1;
}

// JAX uniform(lo=nextafter(-1,0), hi=1), packed pair; one rounding (= JAX).
__device__ __forceinline__ f32x2 u2_from_bits(uint32_t ba, uint32_t bb) {
    f32x2 f;
    f.x = __uint_as_float((ba >> 9) | 0x3F800000u);
    f.y = __uint_as_float((bb >> 9) | 0x3F800000u);
    f = f - (f32x2){1.0f, 1.0f};  // exact (Sterbenz)
    return __builtin_elementwise_fma(f, (f32x2){2.0f, 2.0f},
                                     (f32x2){-0.99999994f, -0.99999994f});
}

// XLA's ErfInv f32 (Giles 2012), packed pair, with wave-uniform tail skip.
// l = log2(1-x^2) <= 0 ; main path w<5 <=> l > -5/ln2. Values identical to
// the branchless version: tail poly only evaluated when some lane needs it.
__device__ __forceinline__ f32x2 erfinv2(f32x2 x) {
    f32x2 t = __builtin_elementwise_fma(-x, x, (f32x2){1.0f, 1.0f});
    f32x2 l;
    l.x = __builtin_amdgcn_logf(t.x);
    l.y = __builtin_amdgcn_logf(t.y);
    f32x2 wm = __builtin_elementwise_fma((f32x2){NLN2, NLN2}, l,
                                         (f32x2){-2.5f, -2.5f});
#define P9(P, W, C) P = __builtin_elementwise_fma(P, W, (f32x2){C, C});
    f32x2 p1 = {2.81022636e-08f, 2.81022636e-08f};
    P9(p1, wm, 3.43273939e-07f)
    P9(p1, wm, -3.5233877e-06f)
    P9(p1, wm, -4.39150654e-06f)
    P9(p1, wm, 0.00021858087f)
    P9(p1, wm, -0.00125372503f)
    P9(p1, wm, -0.00417768164f)
    P9(p1, wm, 0.246640727f)
    P9(p1, wm, 1.50140941f)
    f32x2 p = p1;
    if (__any((l.x < TAIL_TH) || (l.y < TAIL_TH))) {
        f32x2 sq;
        sq.x = __builtin_amdgcn_sqrtf(-l.x);
        sq.y = __builtin_amdgcn_sqrtf(-l.y);
        f32x2 wt = __builtin_elementwise_fma((f32x2){SQRT_LN2, SQRT_LN2}, sq,
                                             (f32x2){-3.0f, -3.0f});
        f32x2 p2 = {-0.000200214257f, -0.000200214257f};
        P9(p2, wt, 0.000100950558f)
        P9(p2, wt, 0.00134934322f)
        P9(p2, wt, -0.00367342844f)
        P9(p2, wt, 0.00573950773f)
        P9(p2, wt, -0.0076224613f)
        P9(p2, wt, 0.00943887047f)
        P9(p2, wt, 1.00167406f)
        P9(p2, wt, 2.83297682f)
        p.x = (l.x > TAIL_TH) ? p1.x : p2.x;
        p.y = (l.y > TAIL_TH) ? p1.y : p2.y;
    }
#undef P9
    return p * x;
}

__device__ __forceinline__ f32x2 qsum4_pk(f32x2 v) {  // sum within 4-lane group
    f32x2 r = v;
    r.x += __shfl_xor(r.x, 1); r.y += __shfl_xor(r.y, 1);
    r.x += __shfl_xor(r.x, 2); r.y += __shfl_xor(r.y, 2);
    return r;
}
__device__ __forceinline__ float xsum16(float v) {  // sum over lanes w/ same (l&3)
    v += __shfl_xor(v, 4);
    v += __shfl_xor(v, 8);
    v += __shfl_xor(v, 16);
    v += __shfl_xor(v, 32);
    return v;
}

struct SgState {
    f32x2 mu0[2], sv0[2], mu1[2], sv1[2];
    f32x2 as0[2], aq0[2], as1[2], aq1[2];
    uint32_t base;
};

// One sample s for this thread's 4 k's (both batch halves).
__device__ __forceinline__ void sg_sample(SgState& st, int s) {
    f32x2 e0[2], e1[2];
#pragma unroll
    for (int p = 0; p < 2; p++) {
        uint32_t ia = st.base + (uint32_t)(p * 20000) + (uint32_t)s;
        uint32_t ib = ia + 10000u;
        uint32_t a0, a1, b0, b1;
        tf2x32(ia, ia + HALF_N, a0, a1);
        tf2x32(ib, ib + HALF_N, b0, b1);
        f32x2 z0 = erfinv2(u2_from_bits(a0, b0));  // batch b,     (k,k+1)
        f32x2 z1 = erfinv2(u2_from_bits(a1, b1));  // batch b+256, (k,k+1)
        e0[p] = __builtin_elementwise_fma(z0, st.sv0[p], st.mu0[p]);
        e1[p] = __builtin_elementwise_fma(z1, st.sv1[p], st.mu1[p]);
    }
#pragma unroll
    for (int p = 0; p < 2; p++) {
        e0[p].x = __builtin_amdgcn_exp2f(e0[p].x);
        e0[p].y = __builtin_amdgcn_exp2f(e0[p].y);
        e1[p].x = __builtin_amdgcn_exp2f(e1[p].x);
        e1[p].y = __builtin_amdgcn_exp2f(e1[p].y);
    }
    f32x2 q0 = e0[0] + e0[1];
    f32x2 q1 = e1[0] + e1[1];
    f32x2 rr = {q0.x + q0.y, q1.x + q1.y};
    rr = qsum4_pk(rr);                       // full 16-wide row sums (b, b+256)
    f32x2 iv0 = {0.f, 0.f}, iv1 = {0.f, 0.f};
    iv0.x = iv0.y = __builtin_amdgcn_rcpf(rr.x);
    iv1.x = iv1.y = __builtin_amdgcn_rcpf(rr.y);
#pragma unroll
    for (int p = 0; p < 2; p++) {
        f32x2 p0 = e0[p] * iv0;
        f32x2 p1 = e1[p] * iv1;
        st.as0[p] += p0; st.aq0[p] = __builtin_elementwise_fma(p0, p0, st.aq0[p]);
        st.as1[p] += p1; st.aq1[p] = __builtin_elementwise_fma(p1, p1, st.aq1[p]);
    }
}

// Accumulate samples [s_begin, s_end) for batch-row b (and b+256); leaves
// block-reduced partials s_fin[k*4 + {s0,q0,s1,q1}]. Lane a=tid&3 owns
// k in {4a..4a+3}; a 4-lane group shares one sample s. Softmax in log2
// domain (s_mu/s_sv pre-scaled by log2e), no max-subtract (overflow-safe).
__device__ __forceinline__ void sg_accumulate(const float* __restrict__ mean,
                                              const float* __restrict__ var,
                                              int b, int s_begin, int s_end,
                                              float (*s_mu)[16], float (*s_sv)[16],
                                              float* s_red, float* s_fin) {
    const int tid = threadIdx.x;

    if (tid < 32) {
        int h = tid >> 4, k = tid & 15;
        int bg = b + 256 * h;
        s_mu[h][k] = LOG2E * mean[bg * 16 + k];
        s_sv[h][k] = (LOG2E * 1.41421356237309515f) * sqrtf(var[bg * 16 + k]);
    }
    __syncthreads();

    const int a4 = (tid & 3) * 4;   // this lane's k base
    const int sgrp = tid >> 2;      // s-group within block

    SgState st;
#pragma unroll
    for (int p = 0; p < 2; p++) {
        st.mu0[p] = *(const f32x2*)&s_mu[0][a4 + 2 * p];
        st.sv0[p] = *(const f32x2*)&s_sv[0][a4 + 2 * p];
        st.mu1[p] = *(const f32x2*)&s_mu[1][a4 + 2 * p];
        st.sv1[p] = *(const f32x2*)&s_sv[1][a4 + 2 * p];
        st.as0[p] = (f32x2){0.f, 0.f}; st.aq0[p] = (f32x2){0.f, 0.f};
        st.as1[p] = (f32x2){0.f, 0.f}; st.aq1[p] = (f32x2){0.f, 0.f};
    }
    st.base = (uint32_t)((b * 16 + a4) * 10000);

    int s = s_begin + sgrp;
    for (; s + SGROUPS < s_end; s += 2 * SGROUPS) {   // unroll x2: 2 samples in flight
        sg_sample(st, s);
        sg_sample(st, s + SGROUPS);
    }
    for (; s < s_end; s += SGROUPS) sg_sample(st, s);

    // Cross-lane: sum the 16 per-thread scalars over the 16 lanes sharing a.
    const int lane = tid & 63, wave = tid >> 6;
    float vals[16] = { st.as0[0].x, st.aq0[0].x, st.as1[0].x, st.aq1[0].x,
                       st.as0[0].y, st.aq0[0].y, st.as1[0].y, st.aq1[0].y,
                       st.as0[1].x, st.aq0[1].x, st.as1[1].x, st.aq1[1].x,
                       st.as0[1].y, st.aq0[1].y, st.as1[1].y, st.aq1[1].y };
#pragma unroll
    for (int i = 0; i < 16; i++) {
        float r = xsum16(vals[i]);
        if (lane < 4) {  // lane == a
            int k = lane * 4 + (i >> 2);
            s_red[wave * 64 + k * 4 + (i & 3)] = r;
        }
    }
    __syncthreads();

    if (tid < 64) {
        float t = 0.f;
#pragma unroll
        for (int w = 0; w < WAVES; w++) t += s_red[w * 64 + tid];
        s_fin[tid] = t;
    }
    __syncthreads();
}

// ---- split path: 256*NCH blocks write partials to ws ----
template <int NCH>
__global__ __launch_bounds__(THREADS, 8)
void sg_partial(const float* __restrict__ mean, const float* __restrict__ var,
                float* __restrict__ ws) {
    __shared__ __attribute__((aligned(8))) float s_mu[2][16];
    __shared__ __attribute__((aligned(8))) float s_sv[2][16];
    __shared__ float s_red[WAVES * 64], s_fin[64];
    const int b = blockIdx.x / NCH;       // 0..255
    const int chunk = blockIdx.x % NCH;
    const int c0 = chunk * (NSAMP / NCH);
    sg_accumulate(mean, var, b, c0, c0 + NSAMP / NCH, s_mu, s_sv, s_red, s_fin);
    if (threadIdx.x < 64) ws[blockIdx.x * 64 + threadIdx.x] = s_fin[threadIdx.x];
}

__global__ __launch_bounds__(256)
void sg_finalize(const float* __restrict__ ws, float* __restrict__ out, int nch) {
    int t = blockIdx.x * blockDim.x + threadIdx.x;  // 0..8191
    if (t >= 8192) return;
    int k = t & 15, h = (t >> 4) & 1, b = t >> 5;
    float sum = 0.f, sq = 0.f;
    for (int c = 0; c < nch; c++) {
        const float* p = ws + ((b * nch + c) * 64 + k * 4 + 2 * h);
        sum += p[0];
        sq += p[1];
    }
    float mu = sum * (1.0f / 10000.0f);
    float vr = (sq - sum * mu) * (1.0f / 9999.0f);  // unbiased
    int bg = b + 256 * h;
    out[bg * 16 + k] = mu;
    out[8192 + bg * 16 + k] = vr;
}

// ---- fallback (ws too small): single kernel, one block per b ----
__global__ __launch_bounds__(THREADS, 8)
void sg_kernel(const float* __restrict__ mean, const float* __restrict__ var,
               float* __restrict__ out) {
    __shared__ __attribute__((aligned(8))) float s_mu[2][16];
    __shared__ __attribute__((aligned(8))) float s_sv[2][16];
    __shared__ float s_red[WAVES * 64], s_fin[64];
    const int b = blockIdx.x;
    sg_accumulate(mean, var, b, 0, NSAMP, s_mu, s_sv, s_red, s_fin);
    const int tid = threadIdx.x;
    if (tid < 32) {
        int h = tid >> 4, k = tid & 15;
        float sum = s_fin[k * 4 + 2 * h + 0];
        float sq  = s_fin[k * 4 + 2 * h + 1];
        float mu = sum * (1.0f / 10000.0f);
        float vr = (sq - sum * mu) * (1.0f / 9999.0f);
        int bg = b + 256 * h;
        out[bg * 16 + k] = mu;
        out[8192 + bg * 16 + k] = vr;
    }
}

extern "C" void kernel_launch(void* const* d_in, const int* in_sizes, int n_in,
                              void* d_out, int out_size, void* d_ws, size_t ws_size,
                              hipStream_t stream) {
    const float* mean = (const float*)d_in[0];
    const float* var  = (const float*)d_in[1];
    float* out = (float*)d_out;
    float* ws = (float*)d_ws;
    if (ws_size >= 256 * 4 * 64 * sizeof(float)) {   // 256 KiB
        sg_partial<4><<<256 * 4, THREADS, 0, stream>>>(mean, var, ws);
        sg_finalize<<<32, 256, 0, stream>>>(ws, out, 4);
    } else {
        sg_kernel<<<256, THREADS, 0, stream>>>(mean, var, out);
    }
}

// Round 9
// 151.692 us; speedup vs baseline: 1.0432x; 1.0432x over previous
//
#include <hip/hip_runtime.h>
#include <cstdint>
#include <math.h>

// SoftmaxGaussian: out_mean/out_var over 10000 MC softmax samples with
// JAX threefry2x32-exact random draw (key(42), shape (512,16,10000)).
//
//   N = 512*16*10000 ; half = 40,960,000 = 256*16*10000
//   flat j=(b*16+k)*10000+s ; threefry block i: counters (i, i+half),
//   key (0,42) -> (z[j=i], z[j=i+half]) => one call yields (b,k,s) AND
//   (b+256,k,s).
//
// R9: R6/R7/R8 all hit ~172 us despite different VGPR/occupancy/spill mixes.
// Suspect: __shfl_xor row-sums lower to DS-pipe ops (SQ_LDS_BANK_CONFLICT
// 131072 appeared with the cooperative structure) -> 2 serial ~50-cycle LDS
// round-trips inside EVERY sample's softmax dependency chain. Fix: DPP
// quad_perm adds (VALU pipe, ~2 cy). Plus s-loop unroll x2 for ILP.
// Base: R7 (256 thr, launch_bounds(256,4) => 64-VGPR cap, 36 used, clean).
// Empirical cap rule: (512,4)->64, (512,8)->32, (256,4)->64. Tripwire:
// FETCH_SIZE must stay <2MB (no spill).

typedef float f32x2 __attribute__((ext_vector_type(2)));

#define NSAMP 10000
#define HALF_N 40960000u
#define THREADS 256
#define WAVES 4
#define SGROUPS (THREADS / 4)   // 64 s-groups per block

#define LOG2E 1.44269504088896340736f
#define NLN2 -0.69314718055994530942f
#define SQRT_LN2 0.83255461115769775635f
#define TAIL_TH -7.2134752f     // -5/ln2

__device__ __forceinline__ uint32_t rotl32(uint32_t x, int r) {
    return __builtin_rotateleft32(x, (unsigned)r);  // v_alignbit_b32
}

// JAX threefry2x32, key = (0, 42)
__device__ __forceinline__ void tf2x32(uint32_t x0, uint32_t x1,
                                       uint32_t& o0, uint32_t& o1) {
    const uint32_t ks1 = 42u;
    const uint32_t ks2 = 0x1BD11BDAu ^ 42u;
    x1 += ks1;
#define TF_R(r) { x0 += x1; x1 = rotl32(x1, r); x1 ^= x0; }
    TF_R(13) TF_R(15) TF_R(26) TF_R(6)   x0 += ks1; x1 += ks2 + 1u;
    TF_R(17) TF_R(29) TF_R(16) TF_R(24)  x0 += ks2; x1 += 2u;
    TF_R(13) TF_R(15) TF_R(26) TF_R(6)                x1 += ks1 + 3u;
    TF_R(17) TF_R(29) TF_R(16) TF_R(24)  x0 += ks1; x1 += ks2 + 4u;
    TF_R(13) TF_R(15) TF_R(26) TF_R(6)   x0 += ks2; x1 += 5u;
#undef TF_R
    o0 = x0;
    o1 = x1;
}

// JAX uniform(lo=nextafter(-1,0), hi=1), packed pair; one rounding (= JAX).
__device__ __forceinline__ f32x2 u2_from_bits(uint32_t ba, uint32_t bb) {
    f32x2 f;
    f.x = __uint_as_float((ba >> 9) | 0x3F800000u);
    f.y = __uint_as_float((bb >> 9) | 0x3F800000u);
    f = f - (f32x2){1.0f, 1.0f};  // exact (Sterbenz)
    return __builtin_elementwise_fma(f, (f32x2){2.0f, 2.0f},
                                     (f32x2){-0.99999994f, -0.99999994f});
}

// XLA's ErfInv f32 (Giles 2012), packed pair, wave-uniform tail skip.
// l = log2(1-x^2) <= 0 ; main path w<5 <=> l > -5/ln2. Values identical to
// the branchless version: tail poly only evaluated when some lane needs it.
__device__ __forceinline__ f32x2 erfinv2(f32x2 x) {
    f32x2 t = __builtin_elementwise_fma(-x, x, (f32x2){1.0f, 1.0f});
    f32x2 l;
    l.x = __builtin_amdgcn_logf(t.x);
    l.y = __builtin_amdgcn_logf(t.y);
    f32x2 wm = __builtin_elementwise_fma((f32x2){NLN2, NLN2}, l,
                                         (f32x2){-2.5f, -2.5f});
#define P9(P, W, C) P = __builtin_elementwise_fma(P, W, (f32x2){C, C});
    f32x2 p1 = {2.81022636e-08f, 2.81022636e-08f};
    P9(p1, wm, 3.43273939e-07f)
    P9(p1, wm, -3.5233877e-06f)
    P9(p1, wm, -4.39150654e-06f)
    P9(p1, wm, 0.00021858087f)
    P9(p1, wm, -0.00125372503f)
    P9(p1, wm, -0.00417768164f)
    P9(p1, wm, 0.246640727f)
    P9(p1, wm, 1.50140941f)
    f32x2 p = p1;
    if (__any((l.x < TAIL_TH) || (l.y < TAIL_TH))) {
        f32x2 sq;
        sq.x = __builtin_amdgcn_sqrtf(-l.x);
        sq.y = __builtin_amdgcn_sqrtf(-l.y);
        f32x2 wt = __builtin_elementwise_fma((f32x2){SQRT_LN2, SQRT_LN2}, sq,
                                             (f32x2){-3.0f, -3.0f});
        f32x2 p2 = {-0.000200214257f, -0.000200214257f};
        P9(p2, wt, 0.000100950558f)
        P9(p2, wt, 0.00134934322f)
        P9(p2, wt, -0.00367342844f)
        P9(p2, wt, 0.00573950773f)
        P9(p2, wt, -0.0076224613f)
        P9(p2, wt, 0.00943887047f)
        P9(p2, wt, 1.00167406f)
        P9(p2, wt, 2.83297682f)
        p.x = (l.x > TAIL_TH) ? p1.x : p2.x;
        p.y = (l.y > TAIL_TH) ? p1.y : p2.y;
    }
#undef P9
    return p * x;
}

// Sum within each 4-lane group via DPP quad_perm (VALU pipe, no LDS).
__device__ __forceinline__ float qsum4_dpp(float v) {
    // v += lanes[lane^1]: quad_perm [1,0,3,2] = 0xB1
    v += __int_as_float(__builtin_amdgcn_mov_dpp(__float_as_int(v),
                                                 0xB1, 0xF, 0xF, true));
    // v += lanes[lane^2]: quad_perm [2,3,0,1] = 0x4E
    v += __int_as_float(__builtin_amdgcn_mov_dpp(__float_as_int(v),
                                                 0x4E, 0xF, 0xF, true));
    return v;
}
__device__ __forceinline__ float xsum16(float v) {  // epilogue only
    v += __shfl_xor(v, 4);
    v += __shfl_xor(v, 8);
    v += __shfl_xor(v, 16);
    v += __shfl_xor(v, 32);
    return v;
}

struct SgState {
    f32x2 mu0[2], sv0[2], mu1[2], sv1[2];
    f32x2 as0[2], aq0[2], as1[2], aq1[2];
    uint32_t base;
};

// One sample s for this thread's 4 k's (both batch halves).
__device__ __forceinline__ void sg_sample(SgState& st, int s) {
    f32x2 e0[2], e1[2];
#pragma unroll
    for (int p = 0; p < 2; p++) {
        uint32_t ia = st.base + (uint32_t)(p * 20000) + (uint32_t)s;
        uint32_t ib = ia + 10000u;
        uint32_t a0, a1, b0, b1;
        tf2x32(ia, ia + HALF_N, a0, a1);
        tf2x32(ib, ib + HALF_N, b0, b1);
        f32x2 z0 = erfinv2(u2_from_bits(a0, b0));  // batch b,     (k,k+1)
        f32x2 z1 = erfinv2(u2_from_bits(a1, b1));  // batch b+256, (k,k+1)
        e0[p] = __builtin_elementwise_fma(z0, st.sv0[p], st.mu0[p]);
        e1[p] = __builtin_elementwise_fma(z1, st.sv1[p], st.mu1[p]);
    }
#pragma unroll
    for (int p = 0; p < 2; p++) {
        e0[p].x = __builtin_amdgcn_exp2f(e0[p].x);
        e0[p].y = __builtin_amdgcn_exp2f(e0[p].y);
        e1[p].x = __builtin_amdgcn_exp2f(e1[p].x);
        e1[p].y = __builtin_amdgcn_exp2f(e1[p].y);
    }
    f32x2 q0 = e0[0] + e0[1];
    f32x2 q1 = e1[0] + e1[1];
    float r0 = qsum4_dpp(q0.x + q0.y);   // 16-wide row sum, batch b
    float r1 = qsum4_dpp(q1.x + q1.y);   // batch b+256
    float inv0 = __builtin_amdgcn_rcpf(r0);
    float inv1 = __builtin_amdgcn_rcpf(r1);
    f32x2 iv0 = {inv0, inv0}, iv1 = {inv1, inv1};
#pragma unroll
    for (int p = 0; p < 2; p++) {
        f32x2 p0 = e0[p] * iv0;
        f32x2 p1 = e1[p] * iv1;
        st.as0[p] += p0; st.aq0[p] = __builtin_elementwise_fma(p0, p0, st.aq0[p]);
        st.as1[p] += p1; st.aq1[p] = __builtin_elementwise_fma(p1, p1, st.aq1[p]);
    }
}

// Accumulate samples [s_begin, s_end) for batch-row b (and b+256); leaves
// block-reduced partials s_fin[k*4 + {s0,q0,s1,q1}]. Lane a=tid&3 owns
// k in {4a..4a+3}; a 4-lane group shares one sample s. Softmax in log2
// domain (s_mu/s_sv pre-scaled by log2e), no max-subtract (overflow-safe).
__device__ __forceinline__ void sg_accumulate(const float* __restrict__ mean,
                                              const float* __restrict__ var,
                                              int b, int s_begin, int s_end,
                                              float (*s_mu)[16], float (*s_sv)[16],
                                              float* s_red, float* s_fin) {
    const int tid = threadIdx.x;

    if (tid < 32) {
        int h = tid >> 4, k = tid & 15;
        int bg = b + 256 * h;
        s_mu[h][k] = LOG2E * mean[bg * 16 + k];
        s_sv[h][k] = (LOG2E * 1.41421356237309515f) * sqrtf(var[bg * 16 + k]);
    }
    __syncthreads();

    const int a4 = (tid & 3) * 4;   // this lane's k base
    const int sgrp = tid >> 2;      // s-group within block

    SgState st;
#pragma unroll
    for (int p = 0; p < 2; p++) {
        st.mu0[p] = *(const f32x2*)&s_mu[0][a4 + 2 * p];
        st.sv0[p] = *(const f32x2*)&s_sv[0][a4 + 2 * p];
        st.mu1[p] = *(const f32x2*)&s_mu[1][a4 + 2 * p];
        st.sv1[p] = *(const f32x2*)&s_sv[1][a4 + 2 * p];
        st.as0[p] = (f32x2){0.f, 0.f}; st.aq0[p] = (f32x2){0.f, 0.f};
        st.as1[p] = (f32x2){0.f, 0.f}; st.aq1[p] = (f32x2){0.f, 0.f};
    }
    st.base = (uint32_t)((b * 16 + a4) * 10000);

    int s = s_begin + sgrp;
    for (; s + SGROUPS < s_end; s += 2 * SGROUPS) {  // 2 samples in flight
        sg_sample(st, s);
        sg_sample(st, s + SGROUPS);
    }
    for (; s < s_end; s += SGROUPS) sg_sample(st, s);

    // Cross-lane: sum the 16 per-thread scalars over the 16 lanes sharing a.
    const int lane = tid & 63, wave = tid >> 6;
    float vals[16] = { st.as0[0].x, st.aq0[0].x, st.as1[0].x, st.aq1[0].x,
                       st.as0[0].y, st.aq0[0].y, st.as1[0].y, st.aq1[0].y,
                       st.as0[1].x, st.aq0[1].x, st.as1[1].x, st.aq1[1].x,
                       st.as0[1].y, st.aq0[1].y, st.as1[1].y, st.aq1[1].y };
#pragma unroll
    for (int i = 0; i < 16; i++) {
        float r = xsum16(vals[i]);
        if (lane < 4) {  // lane == a
            int k = lane * 4 + (i >> 2);
            s_red[wave * 64 + k * 4 + (i & 3)] = r;
        }
    }
    __syncthreads();

    if (tid < 64) {
        float t = 0.f;
#pragma unroll
        for (int w = 0; w < WAVES; w++) t += s_red[w * 64 + tid];
        s_fin[tid] = t;
    }
    __syncthreads();
}

// ---- split path: 256*NCH blocks write partials to ws ----
template <int NCH>
__global__ __launch_bounds__(THREADS, 4)
void sg_partial(const float* __restrict__ mean, const float* __restrict__ var,
                float* __restrict__ ws) {
    __shared__ __attribute__((aligned(8))) float s_mu[2][16];
    __shared__ __attribute__((aligned(8))) float s_sv[2][16];
    __shared__ float s_red[WAVES * 64], s_fin[64];
    const int b = blockIdx.x / NCH;       // 0..255
    const int chunk = blockIdx.x % NCH;
    const int c0 = chunk * (NSAMP / NCH);
    sg_accumulate(mean, var, b, c0, c0 + NSAMP / NCH, s_mu, s_sv, s_red, s_fin);
    if (threadIdx.x < 64) ws[blockIdx.x * 64 + threadIdx.x] = s_fin[threadIdx.x];
}

__global__ __launch_bounds__(256)
void sg_finalize(const float* __restrict__ ws, float* __restrict__ out, int nch) {
    int t = blockIdx.x * blockDim.x + threadIdx.x;  // 0..8191
    if (t >= 8192) return;
    int k = t & 15, h = (t >> 4) & 1, b = t >> 5;
    float sum = 0.f, sq = 0.f;
    for (int c = 0; c < nch; c++) {
        const float* p = ws + ((b * nch + c) * 64 + k * 4 + 2 * h);
        sum += p[0];
        sq += p[1];
    }
    float mu = sum * (1.0f / 10000.0f);
    float vr = (sq - sum * mu) * (1.0f / 9999.0f);  // unbiased
    int bg = b + 256 * h;
    out[bg * 16 + k] = mu;
    out[8192 + bg * 16 + k] = vr;
}

// ---- fallback (ws too small): single kernel, one block per b ----
__global__ __launch_bounds__(THREADS, 4)
void sg_kernel(const float* __restrict__ mean, const float* __restrict__ var,
               float* __restrict__ out) {
    __shared__ __attribute__((aligned(8))) float s_mu[2][16];
    __shared__ __attribute__((aligned(8))) float s_sv[2][16];
    __shared__ float s_red[WAVES * 64], s_fin[64];
    const int b = blockIdx.x;
    sg_accumulate(mean, var, b, 0, NSAMP, s_mu, s_sv, s_red, s_fin);
    const int tid = threadIdx.x;
    if (tid < 32) {
        int h = tid >> 4, k = tid & 15;
        float sum = s_fin[k * 4 + 2 * h + 0];
        float sq  = s_fin[k * 4 + 2 * h + 1];
        float mu = sum * (1.0f / 10000.0f);
        float vr = (sq - sum * mu) * (1.0f / 9999.0f);
        int bg = b + 256 * h;
        out[bg * 16 + k] = mu;
        out[8192 + bg * 16 + k] = vr;
    }
}

extern "C" void kernel_launch(void* const* d_in, const int* in_sizes, int n_in,
                              void* d_out, int out_size, void* d_ws, size_t ws_size,
                              hipStream_t stream) {
    const float* mean = (const float*)d_in[0];
    const float* var  = (const float*)d_in[1];
    float* out = (float*)d_out;
    float* ws = (float*)d_ws;
    if (ws_size >= 256 * 8 * 64 * sizeof(float)) {          // 512 KiB
        sg_partial<8><<<256 * 8, THREADS, 0, stream>>>(mean, var, ws);
        sg_finalize<<<32, 256, 0, stream>>>(ws, out, 8);
    } else if (ws_size >= 256 * 4 * 64 * sizeof(float)) {   // 256 KiB
        sg_partial<4><<<256 * 4, THREADS, 0, stream>>>(mean, var, ws);
        sg_finalize<<<32, 256, 0, stream>>>(ws, out, 4);
    } else {
        sg_kernel<<<256, THREADS, 0, stream>>>(mean, var, out);
    }
}

// Round 10
// 144.972 us; speedup vs baseline: 1.0916x; 1.0464x over previous
//
#include <hip/hip_runtime.h>
#include <cstdint>
#include <math.h>

// SoftmaxGaussian: out_mean/out_var over 10000 MC softmax samples with
// JAX threefry2x32-exact random draw (key(42), shape (512,16,10000)).
//
// Layout facts:
//   N = 512*16*10000 ; half = 40,960,000 = 256*16*10000
//   flat j=(b*16+k)*10000+s ; threefry block i: counters (i, i+half),
//   key (0,42) -> (z[j=i], z[j=i+half]) => one call yields (b,k,s) AND
//   (b+256,k,s).
//
// R10: scoreboard correction — by HARNESS dur_us (the graded clock) R6's
// 16-k-per-thread packed structure (145.7) beats all cooperative variants
// (R7/R8/R9: 151.7-158.3); rocprof-run durations are replay-skewed and
// misled R7-R9. Also: CDNA4 FP32 peak = 1 fma/lane/cyc, so v_pk_* f32 ops
// halve ISSUE slots but not FP32 execution cycles (explains R4's tiny win).
// So: revert to R6 wholesale + graft the one orthogonal cut it never got,
// the wave-uniform erfinv tail-skip (R8-proven, values bit-identical):
// ~65% of calls skip 9 pk-FMA + 2 sqrt + selects.
// Config rules (R2/R4/R5/R8): launch_bounds 2nd arg w caps VGPR at 256/w;
// (256,2) => natural 104 VGPR, no spill, 4 waves/SIMD.

typedef float f32x2 __attribute__((ext_vector_type(2)));

#define NSAMP 10000
#define HALF_N 40960000u
#define THREADS 256
#define WAVES (THREADS / 64)
#define SPLIT 4
#define CHUNK (NSAMP / SPLIT)  // 2500
#define WS_NEEDED (256 * SPLIT * 64 * sizeof(float))  // 262144 B

#define LOG2E 1.44269504088896340736f
#define NLN2 -0.69314718055994530942f
#define SQRT_LN2 0.83255461115769775635f
#define TAIL_TH -7.2134752f  // -5/ln2: main path iff l = log2(1-x^2) > this

__device__ __forceinline__ uint32_t rotl32(uint32_t x, int r) {
    return __builtin_rotateleft32(x, (unsigned)r);  // v_alignbit_b32
}

// JAX threefry2x32, key = (0, 42)
__device__ __forceinline__ void tf2x32(uint32_t x0, uint32_t x1,
                                       uint32_t& o0, uint32_t& o1) {
    const uint32_t ks1 = 42u;
    const uint32_t ks2 = 0x1BD11BDAu ^ 42u;
    x1 += ks1;
#define TF_R(r) { x0 += x1; x1 = rotl32(x1, r); x1 ^= x0; }
    TF_R(13) TF_R(15) TF_R(26) TF_R(6)   x0 += ks1; x1 += ks2 + 1u;
    TF_R(17) TF_R(29) TF_R(16) TF_R(24)  x0 += ks2; x1 += 2u;
    TF_R(13) TF_R(15) TF_R(26) TF_R(6)                x1 += ks1 + 3u;
    TF_R(17) TF_R(29) TF_R(16) TF_R(24)  x0 += ks1; x1 += ks2 + 4u;
    TF_R(13) TF_R(15) TF_R(26) TF_R(6)   x0 += ks2; x1 += 5u;
#undef TF_R
    o0 = x0;
    o1 = x1;
}

// JAX uniform(lo=nextafter(-1,0), hi=1), packed pair; one rounding (= JAX).
__device__ __forceinline__ f32x2 u2_from_bits(uint32_t ba, uint32_t bb) {
    f32x2 f;
    f.x = __uint_as_float((ba >> 9) | 0x3F800000u);
    f.y = __uint_as_float((bb >> 9) | 0x3F800000u);
    f = f - (f32x2){1.0f, 1.0f};  // exact (Sterbenz)
    return __builtin_elementwise_fma(f, (f32x2){2.0f, 2.0f},
                                     (f32x2){-0.99999994f, -0.99999994f});
}

// XLA's ErfInv f32 (Giles 2012), packed pair, wave-uniform tail skip.
// l = log2(1-x^2) <= 0 ; main path w<5 <=> l > -5/ln2. Values identical to
// the branchless version: tail poly only evaluated when some lane needs it
// (P(any tail in 128 wave-values) ~ 35%).
__device__ __forceinline__ f32x2 erfinv2(f32x2 x) {
    f32x2 t = __builtin_elementwise_fma(-x, x, (f32x2){1.0f, 1.0f});
    f32x2 l;
    l.x = __builtin_amdgcn_logf(t.x);
    l.y = __builtin_amdgcn_logf(t.y);
    f32x2 wm = __builtin_elementwise_fma((f32x2){NLN2, NLN2}, l,
                                         (f32x2){-2.5f, -2.5f});
#define P9(P, W, C) P = __builtin_elementwise_fma(P, W, (f32x2){C, C});
    f32x2 p1 = {2.81022636e-08f, 2.81022636e-08f};
    P9(p1, wm, 3.43273939e-07f)
    P9(p1, wm, -3.5233877e-06f)
    P9(p1, wm, -4.39150654e-06f)
    P9(p1, wm, 0.00021858087f)
    P9(p1, wm, -0.00125372503f)
    P9(p1, wm, -0.00417768164f)
    P9(p1, wm, 0.246640727f)
    P9(p1, wm, 1.50140941f)
    f32x2 p = p1;
    if (__any((l.x < TAIL_TH) || (l.y < TAIL_TH))) {
        f32x2 sq;
        sq.x = __builtin_amdgcn_sqrtf(-l.x);
        sq.y = __builtin_amdgcn_sqrtf(-l.y);
        f32x2 wt = __builtin_elementwise_fma((f32x2){SQRT_LN2, SQRT_LN2}, sq,
                                             (f32x2){-3.0f, -3.0f});
        f32x2 p2 = {-0.000200214257f, -0.000200214257f};
        P9(p2, wt, 0.000100950558f)
        P9(p2, wt, 0.00134934322f)
        P9(p2, wt, -0.00367342844f)
        P9(p2, wt, 0.00573950773f)
        P9(p2, wt, -0.0076224613f)
        P9(p2, wt, 0.00943887047f)
        P9(p2, wt, 1.00167406f)
        P9(p2, wt, 2.83297682f)
        p.x = (l.x > TAIL_TH) ? p1.x : p2.x;
        p.y = (l.y > TAIL_TH) ? p1.y : p2.y;
    }
#undef P9
    return p * x;
}

__device__ __forceinline__ float wave_sum(float v) {  // epilogue only
    v += __shfl_down(v, 32);
    v += __shfl_down(v, 16);
    v += __shfl_down(v, 8);
    v += __shfl_down(v, 4);
    v += __shfl_down(v, 2);
    v += __shfl_down(v, 1);
    return v;
}

// Accumulate samples [s_begin, s_end) for batch-row b (and b+256); leaves
// block-reduced partials {sum0,sq0,sum1,sq1} per k in s_fin[64].
// s_mu/s_sv hold log2e-scaled mean and log2e*sqrt(2*var): softmax in log2
// domain (exp2 = bare v_exp_f32), NO max-subtract (|x| <= ~15 so exp2 is
// overflow-safe and row sums < 2^20).
__device__ __forceinline__ void sg_accumulate(const float* __restrict__ mean,
                                              const float* __restrict__ var,
                                              int b, int s_begin, int s_end,
                                              float (*s_mu)[16], float (*s_sv)[16],
                                              float* s_red, float* s_fin) {
    const int tid = threadIdx.x;

    if (tid < 32) {
        int h = tid >> 4, k = tid & 15;
        int bg = b + 256 * h;
        s_mu[h][k] = LOG2E * mean[bg * 16 + k];
        s_sv[h][k] = (LOG2E * 1.41421356237309515f) * sqrtf(var[bg * 16 + k]);
    }
    __syncthreads();

    f32x2 accs0[8], accq0[8], accs1[8], accq1[8];
#pragma unroll
    for (int kp = 0; kp < 8; kp++) {
        accs0[kp] = (f32x2){0.f, 0.f}; accq0[kp] = (f32x2){0.f, 0.f};
        accs1[kp] = (f32x2){0.f, 0.f}; accq1[kp] = (f32x2){0.f, 0.f};
    }

    const uint32_t base_bk = (uint32_t)(b * 16) * 10000u;

    for (int s = s_begin + tid; s < s_end; s += THREADS) {
        f32x2 e0[8], e1[8];
#pragma unroll
        for (int kp = 0; kp < 8; kp++) {
            uint32_t ia = base_bk + (uint32_t)(kp * 20000) + (uint32_t)s;
            uint32_t ib = ia + 10000u;
            uint32_t a0, a1, b0, b1;
            tf2x32(ia, ia + HALF_N, a0, a1);
            tf2x32(ib, ib + HALF_N, b0, b1);
            f32x2 z0 = erfinv2(u2_from_bits(a0, b0));  // batch b,     k pair
            f32x2 z1 = erfinv2(u2_from_bits(a1, b1));  // batch b+256, k pair
            f32x2 mu0 = *(const f32x2*)&s_mu[0][2 * kp];
            f32x2 sv0 = *(const f32x2*)&s_sv[0][2 * kp];
            f32x2 mu1 = *(const f32x2*)&s_mu[1][2 * kp];
            f32x2 sv1 = *(const f32x2*)&s_sv[1][2 * kp];
            e0[kp] = __builtin_elementwise_fma(z0, sv0, mu0);
            e1[kp] = __builtin_elementwise_fma(z1, sv1, mu1);
        }
        f32x2 sm0 = {0.f, 0.f}, sm1 = {0.f, 0.f};
#pragma unroll
        for (int kp = 0; kp < 8; kp++) {
            f32x2 t0, t1;
            t0.x = __builtin_amdgcn_exp2f(e0[kp].x);
            t0.y = __builtin_amdgcn_exp2f(e0[kp].y);
            t1.x = __builtin_amdgcn_exp2f(e1[kp].x);
            t1.y = __builtin_amdgcn_exp2f(e1[kp].y);
            e0[kp] = t0; sm0 += t0;
            e1[kp] = t1; sm1 += t1;
        }
        float inv0 = __builtin_amdgcn_rcpf(sm0.x + sm0.y);
        float inv1 = __builtin_amdgcn_rcpf(sm1.x + sm1.y);
        f32x2 iv0 = {inv0, inv0}, iv1 = {inv1, inv1};
#pragma unroll
        for (int kp = 0; kp < 8; kp++) {
            f32x2 p0 = e0[kp] * iv0;
            f32x2 p1 = e1[kp] * iv1;
            accs0[kp] += p0;
            accq0[kp] = __builtin_elementwise_fma(p0, p0, accq0[kp]);
            accs1[kp] += p1;
            accq1[kp] = __builtin_elementwise_fma(p1, p1, accq1[kp]);
        }
    }

    const int lane = tid & 63, wave = tid >> 6;
#pragma unroll
    for (int kp = 0; kp < 8; kp++) {
#define RED(val, slot) { float r_ = wave_sum(val); if (lane == 0) s_red[wave * 64 + (slot)] = r_; }
        RED(accs0[kp].x, (2 * kp) * 4 + 0)
        RED(accq0[kp].x, (2 * kp) * 4 + 1)
        RED(accs1[kp].x, (2 * kp) * 4 + 2)
        RED(accq1[kp].x, (2 * kp) * 4 + 3)
        RED(accs0[kp].y, (2 * kp + 1) * 4 + 0)
        RED(accq0[kp].y, (2 * kp + 1) * 4 + 1)
        RED(accs1[kp].y, (2 * kp + 1) * 4 + 2)
        RED(accq1[kp].y, (2 * kp + 1) * 4 + 3)
#undef RED
    }
    __syncthreads();

    if (tid < 64) {
        float t = 0.f;
#pragma unroll
        for (int w = 0; w < WAVES; w++) t += s_red[w * 64 + tid];
        s_fin[tid] = t;
    }
    __syncthreads();
}

// ---- split path: 256*SPLIT blocks write partials to ws ----
__global__ __launch_bounds__(THREADS, 2)
void sg_partial(const float* __restrict__ mean, const float* __restrict__ var,
                float* __restrict__ ws) {
    __shared__ __attribute__((aligned(8))) float s_mu[2][16];
    __shared__ __attribute__((aligned(8))) float s_sv[2][16];
    __shared__ float s_red[WAVES * 64], s_fin[64];
    const int b = blockIdx.x >> 2;       // 0..255
    const int chunk = blockIdx.x & 3;    // 0..SPLIT-1
    sg_accumulate(mean, var, b, chunk * CHUNK, (chunk + 1) * CHUNK,
                  s_mu, s_sv, s_red, s_fin);
    if (threadIdx.x < 64) ws[blockIdx.x * 64 + threadIdx.x] = s_fin[threadIdx.x];
}

__global__ __launch_bounds__(256)
void sg_finalize(const float* __restrict__ ws, float* __restrict__ out) {
    int t = blockIdx.x * blockDim.x + threadIdx.x;  // 0..8191
    if (t >= 8192) return;
    int k = t & 15, h = (t >> 4) & 1, b = t >> 5;
    float sum = 0.f, sq = 0.f;
#pragma unroll
    for (int c = 0; c < SPLIT; c++) {
        const float* p = ws + ((b * SPLIT + c) * 64 + k * 4 + 2 * h);
        sum += p[0];
        sq += p[1];
    }
    float mu = sum * (1.0f / 10000.0f);
    float vr = (sq - sum * mu) * (1.0f / 9999.0f);  // unbiased
    int bg = b + 256 * h;
    out[bg * 16 + k] = mu;
    out[8192 + bg * 16 + k] = vr;
}

// ---- fallback (ws too small): single kernel, one block per b ----
__global__ __launch_bounds__(THREADS, 2)
void sg_kernel(const float* __restrict__ mean, const float* __restrict__ var,
               float* __restrict__ out) {
    __shared__ __attribute__((aligned(8))) float s_mu[2][16];
    __shared__ __attribute__((aligned(8))) float s_sv[2][16];
    __shared__ float s_red[WAVES * 64], s_fin[64];
    const int b = blockIdx.x;
    sg_accumulate(mean, var, b, 0, NSAMP, s_mu, s_sv, s_red, s_fin);
    const int tid = threadIdx.x;
    if (tid < 32) {
        int h = tid >> 4, k = tid & 15;
        float sum = s_fin[k * 4 + 2 * h + 0];
        float sq  = s_fin[k * 4 + 2 * h + 1];
        float mu = sum * (1.0f / 10000.0f);
        float vr = (sq - sum * mu) * (1.0f / 9999.0f);
        int bg = b + 256 * h;
        out[bg * 16 + k] = mu;
        out[8192 + bg * 16 + k] = vr;
    }
}

extern "C" void kernel_launch(void* const* d_in, const int* in_sizes, int n_in,
                              void* d_out, int out_size, void* d_ws, size_t ws_size,
                              hipStream_t stream) {
    const float* mean = (const float*)d_in[0];
    const float* var  = (const float*)d_in[1];
    float* out = (float*)d_out;
    if (ws_size >= WS_NEEDED) {
        float* ws = (float*)d_ws;
        sg_partial<<<256 * SPLIT, THREADS, 0, stream>>>(mean, var, ws);
        sg_finalize<<<32, 256, 0, stream>>>(ws, out);
    } else {
        sg_kernel<<<256, THREADS, 0, stream>>>(mean, var, out);
    }
}